// Round 1
// baseline (170.806 us; speedup 1.0000x reference)
//
#include <hip/hip_runtime.h>
#include <math.h>

// Problem constants (fixed by reference)
//  B=128, N=32, M=64, OBS=128, ACT=16, D_QK=128, D_AV=64, F_IN=144, H=64
// Outputs concatenated: value [B,32,32] @0, ret_weight [B,32,32] @131072,
// weight_other [B,32,64] @262144.

// ---------------------------------------------------------------------------
// Kernel 1: fuse Wqk = W_query @ W_key^T, Wqko = W_query_other @ W_key_other^T
// grid 32 x 256 threads; output ws[0..16383] = Wqk, ws[16384..32767] = Wqko
// ---------------------------------------------------------------------------
__global__ __launch_bounds__(256) void fuse_weights_kernel(
    const float* __restrict__ Wq, const float* __restrict__ Wk,
    const float* __restrict__ Wqo, const float* __restrict__ Wko,
    float* __restrict__ outw)
{
  int bi = blockIdx.x;
  const float* A; const float* Bm; float* O;
  if (bi < 16) { A = Wq;  Bm = Wk;  O = outw; }
  else         { A = Wqo; Bm = Wko; O = outw + 16384; bi -= 16; }
  const int tr = (bi >> 2) << 5;   // row tile offset (c)
  const int tc = (bi & 3) << 5;    // col tile offset (e)
  __shared__ float sA[4096];       // rows tr..tr+31, XOR-swizzled cols
  __shared__ float sB[4096];       // rows tc..tc+31, XOR-swizzled cols
  const int t = threadIdx.x;
  const float4* a4 = (const float4*)(A + tr * 128);
  const float4* b4 = (const float4*)(Bm + tc * 128);
  for (int u = 0; u < 4; ++u) {
    int f = t + u * 256;
    int r = f >> 5, c0 = (f & 31) << 2;
    float4 va = a4[f];
    sA[r*128 + ((c0+0) ^ r)] = va.x;
    sA[r*128 + ((c0+1) ^ r)] = va.y;
    sA[r*128 + ((c0+2) ^ r)] = va.z;
    sA[r*128 + ((c0+3) ^ r)] = va.w;
    float4 vb = b4[f];
    sB[r*128 + ((c0+0) ^ r)] = vb.x;
    sB[r*128 + ((c0+1) ^ r)] = vb.y;
    sB[r*128 + ((c0+2) ^ r)] = vb.z;
    sB[r*128 + ((c0+3) ^ r)] = vb.w;
  }
  __syncthreads();
  const int e = t & 31;
  for (int rr = 0; rr < 4; ++rr) {
    const int cl = (t >> 5) + (rr << 3);
    float acc = 0.f;
    #pragma unroll 8
    for (int d = 0; d < 128; ++d)
      acc += sA[cl*128 + (d ^ cl)] * sB[e*128 + (d ^ e)];
    O[(tr + cl)*128 + tc + e] = acc;  // Wqk[c][e] = sum_d Wq[c,d]*Wk[e,d]
  }
}

// ---------------------------------------------------------------------------
// Kernel 2: the whole network. grid 256 (= B * 2 i-halves) x 256 threads.
// LDS pool (floats), phase-aliased, total 14912 floats = 58.25 KB:
//   [0..4095]      s_states [32][128] swizzled  -> later S[16][64] @0,
//                                                  wavo[16][64] @1024,
//                                                  base[16][64] @2048
//   [4096..4607]   s_act  [32][16]
//   [4608..5119]   s_pol  [32][16]
//   [5120..7199]   U1: P/A_o [16][128] | avA [32][64] | dproj [32][65]
//   [7200..7727]   s_w  [16][33]
//   [7728..8767]   s_wo [16][65]
//   [8768..12863]  U2: states_other tile [32][128] swizzled | avO [64][64]
//   [12864..14911] s_delta [32][64]
// ---------------------------------------------------------------------------
__global__ __launch_bounds__(256) void critic_main_kernel(
    const float* __restrict__ g_states, const float* __restrict__ g_pol,
    const float* __restrict__ g_act, const float* __restrict__ g_so,
    const float* __restrict__ g_ao,
    const float* __restrict__ W_av, const float* __restrict__ W_avo,
    const float* __restrict__ W_f1, const float* __restrict__ W_f2,
    const float* __restrict__ Wqk, const float* __restrict__ Wqko,
    float* __restrict__ out)
{
  const int t = threadIdx.x;
  const int b = blockIdx.x >> 1;
  const int i_base = (blockIdx.x & 1) << 4;   // 0 or 16

  __shared__ float lds[14912];
  float* s_states = lds;            // [32][128] swizzled: [i*128 + (c^i)]
  float* s_act    = lds + 4096;     // [32][16]
  float* s_pol    = lds + 4608;     // [32][16]
  float* s_P      = lds + 5120;     // [16][128]
  float* s_w      = lds + 7200;     // [16][33]
  float* s_wo     = lds + 7728;     // [16][65]
  float* s_u2     = lds + 8768;     // tile [32][128] swizzled / avO [64][64]
  float* s_delta  = lds + 12864;    // [32][64]
  float* s_avA    = lds + 5120;     // alias U1: [32][64]
  float* s_dproj  = lds + 5120;     // alias U1: [32][65]
  float* s_S      = lds;            // alias states: [16][64]
  float* s_wavo   = lds + 1024;     // [16][64]
  float* s_base   = lds + 2048;     // [16][64]

  const float inv_sqrt_dk = 0.08838834764831845f;  // 1/sqrt(128)

  // ---- ph0: load states (swizzled), actions, policies -------------------
  {
    const float4* gs4 = (const float4*)(g_states + b * 4096);
    #pragma unroll
    for (int u = 0; u < 4; ++u) {
      int f = t + u * 256;                 // float4 index 0..1023
      float4 v = gs4[f];
      int i = f >> 5, c0 = (f & 31) << 2;
      s_states[i*128 + ((c0+0) ^ i)] = v.x;
      s_states[i*128 + ((c0+1) ^ i)] = v.y;
      s_states[i*128 + ((c0+2) ^ i)] = v.z;
      s_states[i*128 + ((c0+3) ^ i)] = v.w;
    }
    if (t < 128)      ((float4*)s_act)[t]       = ((const float4*)(g_act + b*512))[t];
    else              ((float4*)s_pol)[t - 128] = ((const float4*)(g_pol + b*512))[t - 128];
  }
  __syncthreads();

  // ---- ph1: P = states[i_base..+16] @ Wqk  -> s_P [16][128] -------------
  {
    const int e0  = (t & 31) << 2;
    const int il0 = (t >> 5) << 1;         // local rows il0, il0+1
    const int r0 = i_base + il0, r1 = r0 + 1;
    float4 a0 = {0,0,0,0}, a1 = {0,0,0,0};
    #pragma unroll 4
    for (int c = 0; c < 128; ++c) {
      float s0 = s_states[r0*128 + (c ^ r0)];
      float s1 = s_states[r1*128 + (c ^ r1)];
      float4 wv = *(const float4*)(Wqk + c*128 + e0);
      a0.x += s0*wv.x; a0.y += s0*wv.y; a0.z += s0*wv.z; a0.w += s0*wv.w;
      a1.x += s1*wv.x; a1.y += s1*wv.y; a1.z += s1*wv.z; a1.w += s1*wv.w;
    }
    *(float4*)(s_P + il0*128 + e0)     = a0;
    *(float4*)(s_P + (il0+1)*128 + e0) = a1;
  }
  __syncthreads();

  // ---- ph2: scores = P @ states^T, softmax rows, write ret_weight -------
  {
    const int j = t & 31;
    #pragma unroll
    for (int rr = 0; rr < 2; ++rr) {
      const int li = (t >> 5) + (rr << 3);
      float acc = 0.f;
      #pragma unroll 8
      for (int e = 0; e < 128; ++e)
        acc += s_P[li*128 + e] * s_states[j*128 + (e ^ j)];
      s_w[li*33 + j] = acc * inv_sqrt_dk;
    }
  }
  __syncthreads();
  if (t < 16) {
    float mx = -1e30f;
    for (int j = 0; j < 32; ++j) mx = fmaxf(mx, s_w[t*33 + j]);
    float sum = 0.f;
    for (int j = 0; j < 32; ++j) { float e = __expf(s_w[t*33 + j] - mx); s_w[t*33 + j] = e; sum += e; }
    float inv = 1.f / sum;
    for (int j = 0; j < 32; ++j) s_w[t*33 + j] *= inv;
  }
  __syncthreads();
  {
    #pragma unroll
    for (int u = 0; u < 2; ++u) {
      int f = t + u * 256;                 // 0..511
      int li = f >> 5, j = f & 31;
      out[131072 + b*1024 + (i_base + li)*32 + j] = s_w[li*33 + j];
    }
  }

  // ---- ph3: A_o = states[i_base..+16] @ Wqko -> s_P ---------------------
  {
    const int e0  = (t & 31) << 2;
    const int il0 = (t >> 5) << 1;
    const int r0 = i_base + il0, r1 = r0 + 1;
    float4 a0 = {0,0,0,0}, a1 = {0,0,0,0};
    #pragma unroll 4
    for (int c = 0; c < 128; ++c) {
      float s0 = s_states[r0*128 + (c ^ r0)];
      float s1 = s_states[r1*128 + (c ^ r1)];
      float4 wv = *(const float4*)(Wqko + c*128 + e0);
      a0.x += s0*wv.x; a0.y += s0*wv.y; a0.z += s0*wv.z; a0.w += s0*wv.w;
      a1.x += s1*wv.x; a1.y += s1*wv.y; a1.z += s1*wv.z; a1.w += s1*wv.w;
    }
    *(float4*)(s_P + il0*128 + e0)     = a0;
    *(float4*)(s_P + (il0+1)*128 + e0) = a1;
  }
  __syncthreads();

  // ---- ph4: scores_other via two states_other tiles, softmax, write -----
  for (int tt = 0; tt < 2; ++tt) {
    const float4* gt4 = (const float4*)(g_so + (b*64 + tt*32) * 128);
    #pragma unroll
    for (int u = 0; u < 4; ++u) {
      int f = t + u * 256;
      float4 v = gt4[f];
      int mm = f >> 5, c0 = (f & 31) << 2;
      s_u2[mm*128 + ((c0+0) ^ mm)] = v.x;
      s_u2[mm*128 + ((c0+1) ^ mm)] = v.y;
      s_u2[mm*128 + ((c0+2) ^ mm)] = v.z;
      s_u2[mm*128 + ((c0+3) ^ mm)] = v.w;
    }
    __syncthreads();
    const int mm = t & 31;
    #pragma unroll
    for (int rr = 0; rr < 2; ++rr) {
      const int li = (t >> 5) + (rr << 3);
      float acc = 0.f;
      #pragma unroll 8
      for (int c = 0; c < 128; ++c)
        acc += s_P[li*128 + c] * s_u2[mm*128 + (c ^ mm)];
      s_wo[li*65 + tt*32 + mm] = acc * inv_sqrt_dk;
    }
    __syncthreads();
  }
  if (t < 16) {
    float mx = -1e30f;
    for (int m = 0; m < 64; ++m) mx = fmaxf(mx, s_wo[t*65 + m]);
    float sum = 0.f;
    for (int m = 0; m < 64; ++m) { float e = __expf(s_wo[t*65 + m] - mx); s_wo[t*65 + m] = e; sum += e; }
    float inv = 1.f / sum;
    for (int m = 0; m < 64; ++m) s_wo[t*65 + m] *= inv;
  }
  __syncthreads();
  {
    #pragma unroll
    for (int u = 0; u < 4; ++u) {
      int f = t + u * 256;                 // 0..1023
      int li = f >> 6, m = f & 63;
      out[262144 + b*2048 + (i_base + li)*64 + m] = s_wo[li*65 + m];
    }
  }

  // ---- ph6: av_actions + delta  (writes U1 avA, s_delta) ----------------
  {
    const int d0 = (t & 7) << 3;
    const int kk = t >> 3;                 // 0..31
    float accB[8] = {0,0,0,0,0,0,0,0};     // shared c<128 part
    #pragma unroll 4
    for (int c = 0; c < 128; ++c) {
      float sv = s_states[kk*128 + (c ^ kk)];
      float4 w0 = *(const float4*)(W_av + c*64 + d0);
      float4 w1 = *(const float4*)(W_av + c*64 + d0 + 4);
      accB[0] += sv*w0.x; accB[1] += sv*w0.y; accB[2] += sv*w0.z; accB[3] += sv*w0.w;
      accB[4] += sv*w1.x; accB[5] += sv*w1.y; accB[6] += sv*w1.z; accB[7] += sv*w1.w;
    }
    float accA[8], accP[8];
    #pragma unroll
    for (int q = 0; q < 8; ++q) { accA[q] = accB[q]; accP[q] = accB[q]; }
    #pragma unroll
    for (int c = 128; c < 144; ++c) {
      float sa = s_act[kk*16 + (c - 128)];
      float sp = s_pol[kk*16 + (c - 128)];
      float4 w0 = *(const float4*)(W_av + c*64 + d0);
      float4 w1 = *(const float4*)(W_av + c*64 + d0 + 4);
      accA[0] += sa*w0.x; accA[1] += sa*w0.y; accA[2] += sa*w0.z; accA[3] += sa*w0.w;
      accA[4] += sa*w1.x; accA[5] += sa*w1.y; accA[6] += sa*w1.z; accA[7] += sa*w1.w;
      accP[0] += sp*w0.x; accP[1] += sp*w0.y; accP[2] += sp*w0.z; accP[3] += sp*w0.w;
      accP[4] += sp*w1.x; accP[5] += sp*w1.y; accP[6] += sp*w1.z; accP[7] += sp*w1.w;
    }
    #pragma unroll
    for (int q = 0; q < 8; ++q) {
      float va = tanhf(accA[q]);
      s_avA[kk*64 + d0 + q]   = va;
      s_delta[kk*64 + d0 + q] = tanhf(accP[q]) - va;
    }
  }

  // ---- ph7: av_other (reads states_other/actions_other from global) -----
  {
    const int d0 = (t & 7) << 3;
    const int m0 = (t >> 3) << 1;          // 0..62 step 2
    float acc[2][8];
    #pragma unroll
    for (int a = 0; a < 2; ++a)
      #pragma unroll
      for (int q = 0; q < 8; ++q) acc[a][q] = 0.f;
    const float* so0 = g_so + (b*64 + m0) * 128;
    const float* so1 = so0 + 128;
    #pragma unroll 4
    for (int c = 0; c < 128; ++c) {
      float sv0 = so0[c], sv1 = so1[c];
      float4 w0 = *(const float4*)(W_avo + c*64 + d0);
      float4 w1 = *(const float4*)(W_avo + c*64 + d0 + 4);
      acc[0][0] += sv0*w0.x; acc[0][1] += sv0*w0.y; acc[0][2] += sv0*w0.z; acc[0][3] += sv0*w0.w;
      acc[0][4] += sv0*w1.x; acc[0][5] += sv0*w1.y; acc[0][6] += sv0*w1.z; acc[0][7] += sv0*w1.w;
      acc[1][0] += sv1*w0.x; acc[1][1] += sv1*w0.y; acc[1][2] += sv1*w0.z; acc[1][3] += sv1*w0.w;
      acc[1][4] += sv1*w1.x; acc[1][5] += sv1*w1.y; acc[1][6] += sv1*w1.z; acc[1][7] += sv1*w1.w;
    }
    const float* ao0 = g_ao + (b*64 + m0) * 16;
    const float* ao1 = ao0 + 16;
    #pragma unroll
    for (int c = 0; c < 16; ++c) {
      float sv0 = ao0[c], sv1 = ao1[c];
      float4 w0 = *(const float4*)(W_avo + (128 + c)*64 + d0);
      float4 w1 = *(const float4*)(W_avo + (128 + c)*64 + d0 + 4);
      acc[0][0] += sv0*w0.x; acc[0][1] += sv0*w0.y; acc[0][2] += sv0*w0.z; acc[0][3] += sv0*w0.w;
      acc[0][4] += sv0*w1.x; acc[0][5] += sv0*w1.y; acc[0][6] += sv0*w1.z; acc[0][7] += sv0*w1.w;
      acc[1][0] += sv1*w0.x; acc[1][1] += sv1*w0.y; acc[1][2] += sv1*w0.z; acc[1][3] += sv1*w0.w;
      acc[1][4] += sv1*w1.x; acc[1][5] += sv1*w1.y; acc[1][6] += sv1*w1.z; acc[1][7] += sv1*w1.w;
    }
    #pragma unroll
    for (int a = 0; a < 2; ++a)
      #pragma unroll
      for (int q = 0; q < 8; ++q)
        s_u2[(m0 + a)*64 + d0 + q] = tanhf(acc[a][q]);   // avO
  }
  __syncthreads();

  // ---- ph8: S = w @ avA ; wavo = wo @ avO  (into old states area) -------
  {
    const int d   = t & 63;
    const int li0 = (t >> 6) << 2;         // rows li0..li0+3
    float accS[4] = {0,0,0,0};
    #pragma unroll 4
    for (int k = 0; k < 32; ++k) {
      float av = s_avA[k*64 + d];
      accS[0] += s_w[(li0+0)*33 + k] * av;
      accS[1] += s_w[(li0+1)*33 + k] * av;
      accS[2] += s_w[(li0+2)*33 + k] * av;
      accS[3] += s_w[(li0+3)*33 + k] * av;
    }
    float accW[4] = {0,0,0,0};
    #pragma unroll 4
    for (int m = 0; m < 64; ++m) {
      float av = s_u2[m*64 + d];           // avO
      accW[0] += s_wo[(li0+0)*65 + m] * av;
      accW[1] += s_wo[(li0+1)*65 + m] * av;
      accW[2] += s_wo[(li0+2)*65 + m] * av;
      accW[3] += s_wo[(li0+3)*65 + m] * av;
    }
    #pragma unroll
    for (int q = 0; q < 4; ++q) {
      s_S[(li0+q)*64 + d]    = accS[q];
      s_wavo[(li0+q)*64 + d] = accW[q];
    }
  }
  __syncthreads();

  // ---- ph9: base = S@Wf1a + wavo@Wf1b ; dproj = delta@Wf1a --------------
  {
    const int hh  = t & 63;
    const int li0 = (t >> 6) << 2;
    float acc[4] = {0,0,0,0};
    #pragma unroll 4
    for (int d = 0; d < 64; ++d) {
      float w1v = W_f1[d*64 + hh];
      float w2v = W_f1[(64 + d)*64 + hh];
      acc[0] += s_S[(li0+0)*64 + d]*w1v + s_wavo[(li0+0)*64 + d]*w2v;
      acc[1] += s_S[(li0+1)*64 + d]*w1v + s_wavo[(li0+1)*64 + d]*w2v;
      acc[2] += s_S[(li0+2)*64 + d]*w1v + s_wavo[(li0+2)*64 + d]*w2v;
      acc[3] += s_S[(li0+3)*64 + d]*w1v + s_wavo[(li0+3)*64 + d]*w2v;
    }
    #pragma unroll
    for (int q = 0; q < 4; ++q) s_base[(li0+q)*64 + hh] = acc[q];
  }
  {
    const int hh = t & 63;
    const int j0 = (t >> 6) << 3;          // 8 rows each
    float acc[8] = {0,0,0,0,0,0,0,0};
    #pragma unroll 4
    for (int d = 0; d < 64; ++d) {
      float w1v = W_f1[d*64 + hh];
      #pragma unroll
      for (int q = 0; q < 8; ++q)
        acc[q] += s_delta[(j0+q)*64 + d] * w1v;
    }
    #pragma unroll
    for (int q = 0; q < 8; ++q) s_dproj[(j0+q)*65 + hh] = acc[q];
  }
  __syncthreads();

  // ---- ph10: value[i][j] = sum_h lrelu(base + w*dproj) * Wf2 ------------
  {
    const int j = t & 31;
    #pragma unroll
    for (int rr = 0; rr < 2; ++rr) {
      const int li = (t >> 5) + (rr << 3);
      const float wij = s_w[li*33 + j];
      float acc = 0.f;
      #pragma unroll 4
      for (int hh = 0; hh < 64; ++hh) {
        float pre = s_base[li*64 + hh] + wij * s_dproj[j*65 + hh];
        float hv = pre > 0.f ? pre : 0.01f * pre;
        acc += hv * W_f2[hh];
      }
      out[b*1024 + (i_base + li)*32 + j] = acc;
    }
  }
}

extern "C" void kernel_launch(void* const* d_in, const int* in_sizes, int n_in,
                              void* d_out, int out_size, void* d_ws, size_t ws_size,
                              hipStream_t stream) {
  const float* states        = (const float*)d_in[0];
  const float* policies      = (const float*)d_in[1];
  const float* actions       = (const float*)d_in[2];
  const float* states_other  = (const float*)d_in[3];
  const float* actions_other = (const float*)d_in[4];
  const float* W_key         = (const float*)d_in[5];
  const float* W_query       = (const float*)d_in[6];
  const float* W_av          = (const float*)d_in[7];
  const float* W_key_other   = (const float*)d_in[8];
  const float* W_query_other = (const float*)d_in[9];
  const float* W_av_other    = (const float*)d_in[10];
  const float* W_f1          = (const float*)d_in[11];
  const float* W_f2          = (const float*)d_in[12];
  float* out = (float*)d_out;
  float* ws  = (float*)d_ws;   // needs 32768 floats = 128 KB

  fuse_weights_kernel<<<32, 256, 0, stream>>>(W_query, W_key, W_query_other,
                                              W_key_other, ws);
  critic_main_kernel<<<256, 256, 0, stream>>>(states, policies, actions,
                                              states_other, actions_other,
                                              W_av, W_av_other, W_f1, W_f2,
                                              ws, ws + 16384, out);
}

// Round 2
// 137.940 us; speedup vs baseline: 1.2383x; 1.2383x over previous
//
#include <hip/hip_runtime.h>
#include <math.h>

// Problem constants (fixed by reference)
//  B=128, N=32, M=64, OBS=128, ACT=16, D_QK=128, D_AV=64, F_IN=144, H=64
// Outputs concatenated: value [B,32,32] @0, ret_weight [B,32,32] @131072,
// weight_other [B,32,64] @262144.
//
// Workspace layout (floats) — requires 1,343,488 floats = 5.25 MB:
//   Wqk    [128,128]  @ 0
//   Wqko   [128,128]  @ 16384
//   avA    [B,32,64]  @ 32768
//   delta  [B,32,64]  @ 294912
//   avO    [B,64,64]  @ 557056
//   dproj  [B,32,64]  @ 1081344

#define WS_WQK   0
#define WS_WQKO  16384
#define WS_AVA   32768
#define WS_DELTA 294912
#define WS_AVO   557056
#define WS_DPROJ 1081344

#define INV_SQRT_DK 0.08838834764831845f  // 1/sqrt(128)

// ---------------------------------------------------------------------------
// K1: independent pre-work. grid 544:
//   [0,32)    Wqk / Wqko fusion tiles
//   [32,288)  avA + delta per (b, k-half)
//   [288,544) avO per (b, m-half)
// ---------------------------------------------------------------------------
__global__ __launch_bounds__(256) void k1_pre(
    const float* __restrict__ g_states, const float* __restrict__ g_pol,
    const float* __restrict__ g_act, const float* __restrict__ g_so,
    const float* __restrict__ g_ao,
    const float* __restrict__ Wq, const float* __restrict__ Wk,
    const float* __restrict__ Wqo, const float* __restrict__ Wko,
    const float* __restrict__ W_av, const float* __restrict__ W_avo,
    float* __restrict__ ws)
{
  __shared__ float pool[8192];   // 32 KB
  const int t = threadIdx.x;
  int blk = blockIdx.x;

  if (blk < 32) {
    // ---- weight fusion: Wqk[c][e] = sum_d Wq[c,d]*Wk[e,d] ----------------
    const float* A; const float* Bm; float* O;
    if (blk < 16) { A = Wq;  Bm = Wk;  O = ws + WS_WQK; }
    else          { A = Wqo; Bm = Wko; O = ws + WS_WQKO; blk -= 16; }
    const int tr = (blk >> 2) << 5;
    const int tc = (blk & 3) << 5;
    float* sA = pool;        // [32][128] swizzled
    float* sB = pool + 4096;
    const float4* a4 = (const float4*)(A + tr * 128);
    const float4* b4 = (const float4*)(Bm + tc * 128);
    #pragma unroll
    for (int u = 0; u < 4; ++u) {
      int f = t + u * 256;
      int r = f >> 5, c0 = (f & 31) << 2;
      float4 va = a4[f];
      sA[r*128 + ((c0+0) ^ r)] = va.x;
      sA[r*128 + ((c0+1) ^ r)] = va.y;
      sA[r*128 + ((c0+2) ^ r)] = va.z;
      sA[r*128 + ((c0+3) ^ r)] = va.w;
      float4 vb = b4[f];
      sB[r*128 + ((c0+0) ^ r)] = vb.x;
      sB[r*128 + ((c0+1) ^ r)] = vb.y;
      sB[r*128 + ((c0+2) ^ r)] = vb.z;
      sB[r*128 + ((c0+3) ^ r)] = vb.w;
    }
    __syncthreads();
    const int e = t & 31;
    #pragma unroll
    for (int rr = 0; rr < 4; ++rr) {
      const int cl = (t >> 5) + (rr << 3);
      float acc = 0.f;
      #pragma unroll 8
      for (int d = 0; d < 128; ++d)
        acc += sA[cl*128 + (d ^ cl)] * sB[e*128 + (d ^ e)];
      O[(tr + cl)*128 + tc + e] = acc;
    }
    return;
  }
  blk -= 32;

  if (blk < 256) {
    // ---- avA + delta for (b, 16-row half) --------------------------------
    const int b = blk >> 1, k0 = (blk & 1) << 4;
    float* s_st = pool;          // [16][128] swizzled
    float* s_ac = pool + 2048;   // [16][16]
    float* s_po = pool + 2304;   // [16][16]
    const float4* gs4 = (const float4*)(g_states + b*4096 + k0*128);
    #pragma unroll
    for (int u = 0; u < 2; ++u) {
      int f = t + u * 256;                 // 0..511
      int r = f >> 5, c0 = (f & 31) << 2;
      float4 v = gs4[f];
      s_st[r*128 + ((c0+0) ^ r)] = v.x;
      s_st[r*128 + ((c0+1) ^ r)] = v.y;
      s_st[r*128 + ((c0+2) ^ r)] = v.z;
      s_st[r*128 + ((c0+3) ^ r)] = v.w;
    }
    if (t < 64)                ((float4*)s_ac)[t]      = ((const float4*)(g_act + b*512 + k0*16))[t];
    else if (t < 128)          ((float4*)s_po)[t - 64] = ((const float4*)(g_pol + b*512 + k0*16))[t - 64];
    __syncthreads();
    const int kk = t >> 4;                 // 0..15
    const int d0 = (t & 15) << 2;          // 0..60
    float accB[4] = {0,0,0,0};
    #pragma unroll 4
    for (int c = 0; c < 128; ++c) {
      float sv = s_st[kk*128 + (c ^ kk)];
      float4 wv = *(const float4*)(W_av + c*64 + d0);
      accB[0] += sv*wv.x; accB[1] += sv*wv.y; accB[2] += sv*wv.z; accB[3] += sv*wv.w;
    }
    float accA[4], accP[4];
    #pragma unroll
    for (int q = 0; q < 4; ++q) { accA[q] = accB[q]; accP[q] = accB[q]; }
    #pragma unroll
    for (int cc = 0; cc < 16; ++cc) {
      float sa = s_ac[kk*16 + cc];
      float sp = s_po[kk*16 + cc];
      float4 wv = *(const float4*)(W_av + (128 + cc)*64 + d0);
      accA[0] += sa*wv.x; accA[1] += sa*wv.y; accA[2] += sa*wv.z; accA[3] += sa*wv.w;
      accP[0] += sp*wv.x; accP[1] += sp*wv.y; accP[2] += sp*wv.z; accP[3] += sp*wv.w;
    }
    #pragma unroll
    for (int q = 0; q < 4; ++q) {
      float va = tanhf(accA[q]);
      ws[WS_AVA   + b*2048 + (k0+kk)*64 + d0 + q] = va;
      ws[WS_DELTA + b*2048 + (k0+kk)*64 + d0 + q] = tanhf(accP[q]) - va;
    }
    return;
  }
  blk -= 256;

  // ---- avO for (b, 32-row half) ------------------------------------------
  {
    const int b = blk >> 1, m0 = (blk & 1) << 5;
    float* s_so = pool;          // [32][128] swizzled
    float* s_ao = pool + 4096;   // [32][16]
    const float4* gt4 = (const float4*)(g_so + (b*64 + m0) * 128);
    #pragma unroll
    for (int u = 0; u < 4; ++u) {
      int f = t + u * 256;
      int r = f >> 5, c0 = (f & 31) << 2;
      float4 v = gt4[f];
      s_so[r*128 + ((c0+0) ^ r)] = v.x;
      s_so[r*128 + ((c0+1) ^ r)] = v.y;
      s_so[r*128 + ((c0+2) ^ r)] = v.z;
      s_so[r*128 + ((c0+3) ^ r)] = v.w;
    }
    if (t < 128) ((float4*)s_ao)[t] = ((const float4*)(g_ao + (b*64 + m0)*16))[t];
    __syncthreads();
    const int mm = t >> 3;                 // 0..31
    const int d0 = (t & 7) << 3;           // 0..56
    float acc[8] = {0,0,0,0,0,0,0,0};
    #pragma unroll 4
    for (int c = 0; c < 128; ++c) {
      float sv = s_so[mm*128 + (c ^ mm)];
      float4 w0 = *(const float4*)(W_avo + c*64 + d0);
      float4 w1 = *(const float4*)(W_avo + c*64 + d0 + 4);
      acc[0] += sv*w0.x; acc[1] += sv*w0.y; acc[2] += sv*w0.z; acc[3] += sv*w0.w;
      acc[4] += sv*w1.x; acc[5] += sv*w1.y; acc[6] += sv*w1.z; acc[7] += sv*w1.w;
    }
    #pragma unroll
    for (int cc = 0; cc < 16; ++cc) {
      float sv = s_ao[mm*16 + cc];
      float4 w0 = *(const float4*)(W_avo + (128 + cc)*64 + d0);
      float4 w1 = *(const float4*)(W_avo + (128 + cc)*64 + d0 + 4);
      acc[0] += sv*w0.x; acc[1] += sv*w0.y; acc[2] += sv*w0.z; acc[3] += sv*w0.w;
      acc[4] += sv*w1.x; acc[5] += sv*w1.y; acc[6] += sv*w1.z; acc[7] += sv*w1.w;
    }
    #pragma unroll
    for (int q = 0; q < 8; ++q)
      ws[WS_AVO + b*4096 + (m0+mm)*64 + d0 + q] = tanhf(acc[q]);
  }
}

// ---------------------------------------------------------------------------
// K2: scores + softmax (+dproj). grid 640:
//   [0,512)   per (b, i-octile of 8 rows): P, scores, shuffle softmax, write
//   [512,640) dproj[b] = delta[b] @ W_f1a
// ---------------------------------------------------------------------------
__global__ __launch_bounds__(256) void k2_scores(
    const float* __restrict__ g_states, const float* __restrict__ g_so,
    const float* __restrict__ W_f1, float* __restrict__ ws,
    float* __restrict__ out)
{
  __shared__ float pool[6664];  // 26.7 KB
  const int t = threadIdx.x;
  int blk = blockIdx.x;

  if (blk < 512) {
    const int b = blk >> 2, i0 = (blk & 3) << 3;
    float* s_st = pool;          // [32][128] swizzled (reused for so tiles)
    float* s_P  = pool + 4096;   // [8][256]: P1 at cols 0..127, P2 at 128..255
    float* s_wo = pool + 6144;   // [8][65]

    const float4* gs4 = (const float4*)(g_states + b * 4096);
    #pragma unroll
    for (int u = 0; u < 4; ++u) {
      int f = t + u * 256;
      int r = f >> 5, c0 = (f & 31) << 2;
      float4 v = gs4[f];
      s_st[r*128 + ((c0+0) ^ r)] = v.x;
      s_st[r*128 + ((c0+1) ^ r)] = v.y;
      s_st[r*128 + ((c0+2) ^ r)] = v.z;
      s_st[r*128 + ((c0+3) ^ r)] = v.w;
    }
    __syncthreads();

    // P[r, :] = states[i0+r, :] @ [Wqk | Wqko]
    {
      const int r = t >> 5, e0 = (t & 31) << 2, row = i0 + r;
      const float* wqk  = ws + WS_WQK;
      const float* wqko = ws + WS_WQKO;
      float4 a1 = {0,0,0,0}, a2 = {0,0,0,0};
      #pragma unroll 4
      for (int c = 0; c < 128; ++c) {
        float sv = s_st[row*128 + (c ^ row)];
        float4 w1 = *(const float4*)(wqk  + c*128 + e0);
        float4 w2 = *(const float4*)(wqko + c*128 + e0);
        a1.x += sv*w1.x; a1.y += sv*w1.y; a1.z += sv*w1.z; a1.w += sv*w1.w;
        a2.x += sv*w2.x; a2.y += sv*w2.y; a2.z += sv*w2.z; a2.w += sv*w2.w;
      }
      *(float4*)(s_P + r*256 + e0)       = a1;
      *(float4*)(s_P + r*256 + 128 + e0) = a2;
    }
    __syncthreads();

    // self-attention scores + register softmax (width-32 shuffles)
    {
      const int r = t >> 5, j = t & 31;
      float acc = 0.f;
      #pragma unroll 8
      for (int e = 0; e < 128; ++e)
        acc += s_P[r*256 + e] * s_st[j*128 + (e ^ j)];
      acc *= INV_SQRT_DK;
      float mx = acc;
      for (int off = 16; off; off >>= 1) mx = fmaxf(mx, __shfl_xor(mx, off, 32));
      float ev = __expf(acc - mx);
      float sum = ev;
      for (int off = 16; off; off >>= 1) sum += __shfl_xor(sum, off, 32);
      out[131072 + b*1024 + (i0 + r)*32 + j] = ev / sum;
    }
    __syncthreads();

    // other-attention scores over two states_other tiles
    for (int tt = 0; tt < 2; ++tt) {
      const float4* gt4 = (const float4*)(g_so + (b*64 + tt*32) * 128);
      #pragma unroll
      for (int u = 0; u < 4; ++u) {
        int f = t + u * 256;
        int r = f >> 5, c0 = (f & 31) << 2;
        float4 v = gt4[f];
        s_st[r*128 + ((c0+0) ^ r)] = v.x;
        s_st[r*128 + ((c0+1) ^ r)] = v.y;
        s_st[r*128 + ((c0+2) ^ r)] = v.z;
        s_st[r*128 + ((c0+3) ^ r)] = v.w;
      }
      __syncthreads();
      const int r = t >> 5, m = t & 31;
      float acc = 0.f;
      #pragma unroll 8
      for (int c = 0; c < 128; ++c)
        acc += s_P[r*256 + 128 + c] * s_st[m*128 + (c ^ m)];
      s_wo[r*65 + tt*32 + m] = acc * INV_SQRT_DK;
      __syncthreads();
    }

    // softmax wo (width-64 shuffles, 4 waves x 2 passes cover 8 rows)
    #pragma unroll
    for (int p = 0; p < 2; ++p) {
      const int r = (t >> 6) + (p << 2), l = t & 63;
      float v = s_wo[r*65 + l];
      float mx = v;
      for (int off = 32; off; off >>= 1) mx = fmaxf(mx, __shfl_xor(mx, off, 64));
      float ev = __expf(v - mx);
      float sum = ev;
      for (int off = 32; off; off >>= 1) sum += __shfl_xor(sum, off, 64);
      out[262144 + b*2048 + (i0 + r)*64 + l] = ev / sum;
    }
    return;
  }

  // ---- dproj[b] = delta[b] @ W_f1(top half) ------------------------------
  {
    const int b = blk - 512;
    float* s_d = pool;           // [32][64]
    #pragma unroll
    for (int u = 0; u < 2; ++u)
      ((float4*)s_d)[t + u*256] = ((const float4*)(ws + WS_DELTA + b*2048))[t + u*256];
    __syncthreads();
    const int h = t & 63, j0 = (t >> 6) << 3;
    float acc[8] = {0,0,0,0,0,0,0,0};
    #pragma unroll 4
    for (int d = 0; d < 64; ++d) {
      float w1v = W_f1[d*64 + h];
      #pragma unroll
      for (int q = 0; q < 8; ++q)
        acc[q] += s_d[(j0+q)*64 + d] * w1v;
    }
    #pragma unroll
    for (int q = 0; q < 8; ++q)
      ws[WS_DPROJ + b*2048 + (j0+q)*64 + h] = acc[q];
  }
}

// ---------------------------------------------------------------------------
// K3: S/wavo/base/value per (b, i-octile). grid 512.
// ---------------------------------------------------------------------------
__global__ __launch_bounds__(256) void k3_value(
    const float* __restrict__ W_f1, const float* __restrict__ W_f2,
    const float* __restrict__ ws, float* __restrict__ out)
{
  __shared__ float s_avA[2048];   // [32][64]
  __shared__ float s_avO[4096];   // [64][64]
  __shared__ float s_dproj[2080]; // [32][65]
  __shared__ float s_w[264];      // [8][33]
  __shared__ float s_wo[520];     // [8][65]
  __shared__ float s_S[512];      // [8][64]
  __shared__ float s_wavo[512];   // [8][64]
  __shared__ float s_base[512];   // [8][64]
  __shared__ float s_wf2[64];
  const int t = threadIdx.x;
  const int b = blockIdx.x >> 2, i0 = (blockIdx.x & 3) << 3;

  // ---- stage everything ---------------------------------------------------
  #pragma unroll
  for (int u = 0; u < 2; ++u)
    ((float4*)s_avA)[t + u*256] = ((const float4*)(ws + WS_AVA + b*2048))[t + u*256];
  #pragma unroll
  for (int u = 0; u < 4; ++u)
    ((float4*)s_avO)[t + u*256] = ((const float4*)(ws + WS_AVO + b*4096))[t + u*256];
  #pragma unroll
  for (int u = 0; u < 8; ++u) {
    int idx = t + u*256;
    s_dproj[(idx >> 6)*65 + (idx & 63)] = ws[WS_DPROJ + b*2048 + idx];
  }
  {
    int li = t >> 5, j = t & 31;
    s_w[li*33 + j] = out[131072 + b*1024 + (i0 + li)*32 + j];
  }
  #pragma unroll
  for (int u = 0; u < 2; ++u) {
    int idx = t + u*256;
    int li = idx >> 6, m = idx & 63;
    s_wo[li*65 + m] = out[262144 + b*2048 + (i0 + li)*64 + m];
  }
  if (t < 64) s_wf2[t] = W_f2[t];
  __syncthreads();

  // ---- S = w @ avA ; wavo = wo @ avO -------------------------------------
  {
    const int d = t & 63, g = (t >> 6) << 1;
    float a0 = 0.f, a1 = 0.f;
    #pragma unroll 4
    for (int k = 0; k < 32; ++k) {
      float av = s_avA[k*64 + d];
      a0 += s_w[g*33 + k] * av;
      a1 += s_w[(g+1)*33 + k] * av;
    }
    s_S[g*64 + d] = a0; s_S[(g+1)*64 + d] = a1;
    float b0 = 0.f, b1 = 0.f;
    #pragma unroll 4
    for (int m = 0; m < 64; ++m) {
      float av = s_avO[m*64 + d];
      b0 += s_wo[g*65 + m] * av;
      b1 += s_wo[(g+1)*65 + m] * av;
    }
    s_wavo[g*64 + d] = b0; s_wavo[(g+1)*64 + d] = b1;
  }
  __syncthreads();

  // ---- base = S@Wf1a + wavo@Wf1b -----------------------------------------
  {
    const int h = t & 63, g = (t >> 6) << 1;
    float a0 = 0.f, a1 = 0.f;
    #pragma unroll 4
    for (int d = 0; d < 64; ++d) {
      float w1v = W_f1[d*64 + h];
      float w2v = W_f1[(64 + d)*64 + h];
      a0 += s_S[g*64 + d]*w1v + s_wavo[g*64 + d]*w2v;
      a1 += s_S[(g+1)*64 + d]*w1v + s_wavo[(g+1)*64 + d]*w2v;
    }
    s_base[g*64 + h] = a0; s_base[(g+1)*64 + h] = a1;
  }
  __syncthreads();

  // ---- value[i][j] = sum_h lrelu(base[i,h] + w[i,j]*dproj[j,h]) * Wf2[h] --
  {
    const int i = t >> 5, j = t & 31;
    const float wij = s_w[i*33 + j];
    float acc = 0.f;
    #pragma unroll 4
    for (int h = 0; h < 64; ++h) {
      float pre = s_base[i*64 + h] + wij * s_dproj[j*65 + h];
      float hv = pre > 0.f ? pre : 0.01f * pre;
      acc += hv * s_wf2[h];
    }
    out[b*1024 + (i0 + i)*32 + j] = acc;
  }
}

extern "C" void kernel_launch(void* const* d_in, const int* in_sizes, int n_in,
                              void* d_out, int out_size, void* d_ws, size_t ws_size,
                              hipStream_t stream) {
  const float* states        = (const float*)d_in[0];
  const float* policies      = (const float*)d_in[1];
  const float* actions       = (const float*)d_in[2];
  const float* states_other  = (const float*)d_in[3];
  const float* actions_other = (const float*)d_in[4];
  const float* W_key         = (const float*)d_in[5];
  const float* W_query       = (const float*)d_in[6];
  const float* W_av          = (const float*)d_in[7];
  const float* W_key_other   = (const float*)d_in[8];
  const float* W_query_other = (const float*)d_in[9];
  const float* W_av_other    = (const float*)d_in[10];
  const float* W_f1          = (const float*)d_in[11];
  const float* W_f2          = (const float*)d_in[12];
  float* out = (float*)d_out;
  float* ws  = (float*)d_ws;   // needs 5.25 MB

  k1_pre<<<544, 256, 0, stream>>>(states, policies, actions, states_other,
                                  actions_other, W_query, W_key,
                                  W_query_other, W_key_other, W_av, W_av_other,
                                  ws);
  k2_scores<<<640, 256, 0, stream>>>(states, states_other, W_f1, ws, out);
  k3_value<<<512, 256, 0, stream>>>(W_f1, W_f2, ws, out);
}

// Round 3
// 132.217 us; speedup vs baseline: 1.2919x; 1.0433x over previous
//
#include <hip/hip_runtime.h>
#include <math.h>

// Problem constants (fixed by reference)
//  B=128, N=32, M=64, OBS=128, ACT=16, D_QK=128, D_AV=64, F_IN=144, H=64
// Outputs concatenated: value [B,32,32] @0, ret_weight [B,32,32] @131072,
// weight_other [B,32,64] @262144.
//
// Workspace (floats), 1,081,344 floats = 4.125 MB:
#define WS_WQK   0         // [128][128]
#define WS_WQKO  16384     // [128][128]
#define WS_AVA   32768     // [B][32][64]
#define WS_AVO   294912    // [B][64][64]
#define WS_DPROJ 819200    // [B][32][64]

#define INV_SQRT_DK 0.08838834764831845f  // 1/sqrt(128)

__device__ __forceinline__ float dot4(float4 a, float4 b) {
  return a.x*b.x + a.y*b.y + a.z*b.z + a.w*b.w;
}

// ---------------------------------------------------------------------------
// K1: independent pre-work. grid 416:
//   [0,32)    Wqk / Wqko fusion tiles (32x32 out each)
//   [32,160)  avA + delta + dproj per b
//   [160,416) avO per (b, m-half)
// ---------------------------------------------------------------------------
__global__ __launch_bounds__(256) void k1_pre(
    const float* __restrict__ g_states, const float* __restrict__ g_pol,
    const float* __restrict__ g_act, const float* __restrict__ g_so,
    const float* __restrict__ g_ao,
    const float* __restrict__ Wq, const float* __restrict__ Wk,
    const float* __restrict__ Wqo, const float* __restrict__ Wko,
    const float* __restrict__ W_av, const float* __restrict__ W_avo,
    const float* __restrict__ W_f1, float* __restrict__ ws)
{
  __shared__ float pool[8448];   // 33 KB
  const int t = threadIdx.x;
  int blk = blockIdx.x;

  if (blk < 32) {
    // ---- weight fusion: Wqk[c][e] = sum_d Wq[c,d]*Wk[e,d] ----------------
    const float* A; const float* Bm; float* O;
    if (blk < 16) { A = Wq;  Bm = Wk;  O = ws + WS_WQK; }
    else          { A = Wqo; Bm = Wko; O = ws + WS_WQKO; blk -= 16; }
    const int tr = (blk >> 2) << 5;   // output row tile (c)
    const int tc = (blk & 3) << 5;    // output col tile (e)
    float* sA = pool;                 // [32][132]
    float* sB = pool + 4224;          // [32][132]
    const float4* a4 = (const float4*)(A + tr * 128);
    const float4* b4 = (const float4*)(Bm + tc * 128);
    #pragma unroll
    for (int u = 0; u < 4; ++u) {
      int f = t + u * 256;
      int r = f >> 5, c4 = f & 31;
      *(float4*)(sA + r*132 + c4*4) = a4[f];
      *(float4*)(sB + r*132 + c4*4) = b4[f];
    }
    __syncthreads();
    const int e = t & 31, cl0 = t >> 5;
    float acc[4] = {0,0,0,0};
    #pragma unroll 4
    for (int d4 = 0; d4 < 32; ++d4) {
      float4 bv = *(const float4*)(sB + e*132 + d4*4);
      #pragma unroll
      for (int rr = 0; rr < 4; ++rr) {
        float4 av = *(const float4*)(sA + (cl0 + rr*8)*132 + d4*4);
        acc[rr] += dot4(av, bv);
      }
    }
    #pragma unroll
    for (int rr = 0; rr < 4; ++rr)
      O[(tr + cl0 + rr*8)*128 + tc + e] = acc[rr];
    return;
  }
  blk -= 32;

  if (blk < 128) {
    // ---- avA + delta + dproj per b ---------------------------------------
    const int b = blk;
    float* s_st = pool;           // [32][132]
    float* s_ac = pool + 4224;    // [32][16]
    float* s_po = pool + 4736;    // [32][16]
    float* s_dl = pool + 5248;    // delta [32][68]
    const float4* gs4 = (const float4*)(g_states + b*4096);
    #pragma unroll
    for (int u = 0; u < 4; ++u) {
      int f = t + u * 256;
      int r = f >> 5, c4 = f & 31;
      *(float4*)(s_st + r*132 + c4*4) = gs4[f];
    }
    if (t < 128)      ((float4*)s_ac)[t]       = ((const float4*)(g_act + b*512))[t];
    else              ((float4*)s_po)[t - 128] = ((const float4*)(g_pol + b*512))[t - 128];
    __syncthreads();
    {
      const int kk = t >> 3;            // 0..31
      const int d0 = (t & 7) << 3;      // 0..56
      float accB[8] = {0,0,0,0,0,0,0,0};
      #pragma unroll 2
      for (int c4 = 0; c4 < 32; ++c4) {
        float4 s4 = *(const float4*)(s_st + kk*132 + c4*4);
        const float sv[4] = {s4.x, s4.y, s4.z, s4.w};
        #pragma unroll
        for (int k = 0; k < 4; ++k) {
          int c = c4*4 + k;
          float4 w0 = *(const float4*)(W_av + c*64 + d0);
          float4 w1 = *(const float4*)(W_av + c*64 + d0 + 4);
          accB[0] += sv[k]*w0.x; accB[1] += sv[k]*w0.y;
          accB[2] += sv[k]*w0.z; accB[3] += sv[k]*w0.w;
          accB[4] += sv[k]*w1.x; accB[5] += sv[k]*w1.y;
          accB[6] += sv[k]*w1.z; accB[7] += sv[k]*w1.w;
        }
      }
      float accA[8], accP[8];
      #pragma unroll
      for (int q = 0; q < 8; ++q) { accA[q] = accB[q]; accP[q] = accB[q]; }
      #pragma unroll
      for (int cc = 0; cc < 16; ++cc) {
        float sa = s_ac[kk*16 + cc];
        float sp = s_po[kk*16 + cc];
        float4 w0 = *(const float4*)(W_av + (128 + cc)*64 + d0);
        float4 w1 = *(const float4*)(W_av + (128 + cc)*64 + d0 + 4);
        accA[0] += sa*w0.x; accA[1] += sa*w0.y; accA[2] += sa*w0.z; accA[3] += sa*w0.w;
        accA[4] += sa*w1.x; accA[5] += sa*w1.y; accA[6] += sa*w1.z; accA[7] += sa*w1.w;
        accP[0] += sp*w0.x; accP[1] += sp*w0.y; accP[2] += sp*w0.z; accP[3] += sp*w0.w;
        accP[4] += sp*w1.x; accP[5] += sp*w1.y; accP[6] += sp*w1.z; accP[7] += sp*w1.w;
      }
      float4 va0, va1, dl0, dl1;
      va0.x = tanhf(accA[0]); va0.y = tanhf(accA[1]);
      va0.z = tanhf(accA[2]); va0.w = tanhf(accA[3]);
      va1.x = tanhf(accA[4]); va1.y = tanhf(accA[5]);
      va1.z = tanhf(accA[6]); va1.w = tanhf(accA[7]);
      dl0.x = tanhf(accP[0]) - va0.x; dl0.y = tanhf(accP[1]) - va0.y;
      dl0.z = tanhf(accP[2]) - va0.z; dl0.w = tanhf(accP[3]) - va0.w;
      dl1.x = tanhf(accP[4]) - va1.x; dl1.y = tanhf(accP[5]) - va1.y;
      dl1.z = tanhf(accP[6]) - va1.z; dl1.w = tanhf(accP[7]) - va1.w;
      *(float4*)(ws + WS_AVA + b*2048 + kk*64 + d0)     = va0;
      *(float4*)(ws + WS_AVA + b*2048 + kk*64 + d0 + 4) = va1;
      *(float4*)(s_dl + kk*68 + d0)     = dl0;
      *(float4*)(s_dl + kk*68 + d0 + 4) = dl1;
    }
    __syncthreads();
    {
      // dproj[j][h] = sum_d delta[j][d] * W_f1[d][h]
      const int h = t & 63;
      const int j0 = (t >> 6) << 3;     // 8 rows per thread
      float acc[8] = {0,0,0,0,0,0,0,0};
      #pragma unroll 4
      for (int d4 = 0; d4 < 16; ++d4) {
        float w0 = W_f1[(d4*4+0)*64 + h];
        float w1 = W_f1[(d4*4+1)*64 + h];
        float w2 = W_f1[(d4*4+2)*64 + h];
        float w3 = W_f1[(d4*4+3)*64 + h];
        #pragma unroll
        for (int q = 0; q < 8; ++q) {
          float4 dv = *(const float4*)(s_dl + (j0+q)*68 + d4*4);
          acc[q] += dv.x*w0 + dv.y*w1 + dv.z*w2 + dv.w*w3;
        }
      }
      #pragma unroll
      for (int q = 0; q < 8; ++q)
        ws[WS_DPROJ + b*2048 + (j0+q)*64 + h] = acc[q];
    }
    return;
  }
  blk -= 128;

  // ---- avO per (b, 32-row half) ------------------------------------------
  {
    const int b = blk >> 1, m0 = (blk & 1) << 5;
    float* s_so = pool;           // [32][132]
    float* s_ao = pool + 4224;    // [32][16]
    const float4* gt4 = (const float4*)(g_so + (b*64 + m0) * 128);
    #pragma unroll
    for (int u = 0; u < 4; ++u) {
      int f = t + u * 256;
      int r = f >> 5, c4 = f & 31;
      *(float4*)(s_so + r*132 + c4*4) = gt4[f];
    }
    if (t < 128) ((float4*)s_ao)[t] = ((const float4*)(g_ao + (b*64 + m0)*16))[t];
    __syncthreads();
    const int mm = t >> 3;
    const int d0 = (t & 7) << 3;
    float acc[8] = {0,0,0,0,0,0,0,0};
    #pragma unroll 2
    for (int c4 = 0; c4 < 32; ++c4) {
      float4 s4 = *(const float4*)(s_so + mm*132 + c4*4);
      const float sv[4] = {s4.x, s4.y, s4.z, s4.w};
      #pragma unroll
      for (int k = 0; k < 4; ++k) {
        int c = c4*4 + k;
        float4 w0 = *(const float4*)(W_avo + c*64 + d0);
        float4 w1 = *(const float4*)(W_avo + c*64 + d0 + 4);
        acc[0] += sv[k]*w0.x; acc[1] += sv[k]*w0.y; acc[2] += sv[k]*w0.z; acc[3] += sv[k]*w0.w;
        acc[4] += sv[k]*w1.x; acc[5] += sv[k]*w1.y; acc[6] += sv[k]*w1.z; acc[7] += sv[k]*w1.w;
      }
    }
    #pragma unroll
    for (int cc = 0; cc < 16; ++cc) {
      float sv = s_ao[mm*16 + cc];
      float4 w0 = *(const float4*)(W_avo + (128 + cc)*64 + d0);
      float4 w1 = *(const float4*)(W_avo + (128 + cc)*64 + d0 + 4);
      acc[0] += sv*w0.x; acc[1] += sv*w0.y; acc[2] += sv*w0.z; acc[3] += sv*w0.w;
      acc[4] += sv*w1.x; acc[5] += sv*w1.y; acc[6] += sv*w1.z; acc[7] += sv*w1.w;
    }
    float4 o0, o1;
    o0.x = tanhf(acc[0]); o0.y = tanhf(acc[1]); o0.z = tanhf(acc[2]); o0.w = tanhf(acc[3]);
    o1.x = tanhf(acc[4]); o1.y = tanhf(acc[5]); o1.z = tanhf(acc[6]); o1.w = tanhf(acc[7]);
    *(float4*)(ws + WS_AVO + b*4096 + (m0+mm)*64 + d0)     = o0;
    *(float4*)(ws + WS_AVO + b*4096 + (m0+mm)*64 + d0 + 4) = o1;
  }
}

// ---------------------------------------------------------------------------
// K2: everything after pre-work, per (b, i-octile). grid 512.
// LDS pool (floats), 11232 = 43.9 KB:
//   A    @0     [4352]: states [32][132] / so tiles [32][132] / avO [64][68]
//   Bq   @4352  [2176]: P1 [8][132] + P2 [8][132] / avA [32][68]
//   dp   @6528  [2176]: dproj [32][68]
//   w    @8704  [288] : [8][36]
//   wo   @8992  [544] : [8][68]
//   S    @9536  [544] : [8][68]
//   wavo @10080 [544] : [8][68]
//   base @10624 [544] : [8][68]
//   wf2  @11168 [64]
// ---------------------------------------------------------------------------
__global__ __launch_bounds__(256) void k2_main(
    const float* __restrict__ g_states, const float* __restrict__ g_so,
    const float* __restrict__ W_f1, const float* __restrict__ W_f2,
    const float* __restrict__ ws, float* __restrict__ out)
{
  __shared__ float pool[11232];
  float* s_st   = pool;
  float* s_P1   = pool + 4352;
  float* s_P2   = pool + 4352 + 1056;
  float* s_avO  = pool;            // alias A
  float* s_avA  = pool + 4352;     // alias Bq
  float* s_dp   = pool + 6528;
  float* s_w    = pool + 8704;
  float* s_wo   = pool + 8992;
  float* s_S    = pool + 9536;
  float* s_wavo = pool + 10080;
  float* s_base = pool + 10624;
  float* s_wf2  = pool + 11168;

  const int t = threadIdx.x;
  const int b = blockIdx.x >> 2;
  const int i0 = (blockIdx.x & 3) << 3;

  // ---- ph1: stage dproj, wf2, states ------------------------------------
  #pragma unroll
  for (int u = 0; u < 2; ++u) {
    int f = t + u * 256;                  // 0..511 float4
    int j = f >> 4, dq = f & 15;
    *(float4*)(s_dp + j*68 + dq*4) = ((const float4*)(ws + WS_DPROJ + b*2048))[f];
  }
  if (t < 16) *(float4*)(s_wf2 + t*4) = ((const float4*)W_f2)[t];
  {
    const float4* gs4 = (const float4*)(g_states + b * 4096);
    #pragma unroll
    for (int u = 0; u < 4; ++u) {
      int f = t + u * 256;
      int r = f >> 5, c4 = f & 31;
      *(float4*)(s_st + r*132 + c4*4) = gs4[f];
    }
  }
  __syncthreads();

  // ---- ph2: P = states[i0..i0+8] @ [Wqk | Wqko] --------------------------
  {
    const int r = t >> 5, e0 = (t & 31) << 2, row = i0 + r;
    const float* wqk  = ws + WS_WQK;
    const float* wqko = ws + WS_WQKO;
    float4 a1 = {0,0,0,0}, a2 = {0,0,0,0};
    #pragma unroll 2
    for (int c4 = 0; c4 < 32; ++c4) {
      float4 s4 = *(const float4*)(s_st + row*132 + c4*4);
      const float sv[4] = {s4.x, s4.y, s4.z, s4.w};
      #pragma unroll
      for (int k = 0; k < 4; ++k) {
        int c = c4*4 + k;
        float4 w1 = *(const float4*)(wqk  + c*128 + e0);
        float4 w2 = *(const float4*)(wqko + c*128 + e0);
        a1.x += sv[k]*w1.x; a1.y += sv[k]*w1.y; a1.z += sv[k]*w1.z; a1.w += sv[k]*w1.w;
        a2.x += sv[k]*w2.x; a2.y += sv[k]*w2.y; a2.z += sv[k]*w2.z; a2.w += sv[k]*w2.w;
      }
    }
    *(float4*)(s_P1 + r*132 + e0) = a1;
    *(float4*)(s_P2 + r*132 + e0) = a2;
  }
  __syncthreads();

  // ---- ph3: self scores + register softmax + write ret_weight ------------
  {
    const int r = t >> 5, j = t & 31;
    float acc = 0.f;
    #pragma unroll 8
    for (int e4 = 0; e4 < 32; ++e4) {
      float4 p4  = *(const float4*)(s_P1 + r*132 + e4*4);
      float4 st4 = *(const float4*)(s_st + j*132 + e4*4);
      acc += dot4(p4, st4);
    }
    acc *= INV_SQRT_DK;
    float mx = acc;
    for (int off = 16; off; off >>= 1) mx = fmaxf(mx, __shfl_xor(mx, off, 32));
    float ev = __expf(acc - mx);
    float sum = ev;
    for (int off = 16; off; off >>= 1) sum += __shfl_xor(sum, off, 32);
    float wn = ev / sum;
    out[131072 + b*1024 + (i0 + r)*32 + j] = wn;
    s_w[r*36 + j] = wn;
  }
  __syncthreads();

  // ---- ph4/5: other scores over two states_other tiles -------------------
  for (int tt = 0; tt < 2; ++tt) {
    const float4* gt4 = (const float4*)(g_so + (b*64 + tt*32) * 128);
    #pragma unroll
    for (int u = 0; u < 4; ++u) {
      int f = t + u * 256;
      int r = f >> 5, c4 = f & 31;
      *(float4*)(s_st + r*132 + c4*4) = gt4[f];
    }
    __syncthreads();
    const int r = t >> 5, m = t & 31;
    float acc = 0.f;
    #pragma unroll 8
    for (int c4 = 0; c4 < 32; ++c4) {
      float4 p4  = *(const float4*)(s_P2 + r*132 + c4*4);
      float4 st4 = *(const float4*)(s_st + m*132 + c4*4);
      acc += dot4(p4, st4);
    }
    s_wo[r*68 + tt*32 + m] = acc * INV_SQRT_DK;
    __syncthreads();
  }

  // ---- ph6: softmax wo + write weight_other; stage avA/avO ---------------
  #pragma unroll
  for (int p = 0; p < 2; ++p) {
    const int r = (t >> 6) + (p << 2), l = t & 63;
    float v = s_wo[r*68 + l];
    float mx = v;
    for (int off = 32; off; off >>= 1) mx = fmaxf(mx, __shfl_xor(mx, off, 64));
    float ev = __expf(v - mx);
    float sum = ev;
    for (int off = 32; off; off >>= 1) sum += __shfl_xor(sum, off, 64);
    float wn = ev / sum;
    out[262144 + b*2048 + (i0 + r)*64 + l] = wn;
    s_wo[r*68 + l] = wn;
  }
  #pragma unroll
  for (int u = 0; u < 2; ++u) {
    int f = t + u * 256;
    int k = f >> 4, dq = f & 15;
    *(float4*)(s_avA + k*68 + dq*4) = ((const float4*)(ws + WS_AVA + b*2048))[f];
  }
  #pragma unroll
  for (int u = 0; u < 4; ++u) {
    int f = t + u * 256;
    int m = f >> 4, dq = f & 15;
    *(float4*)(s_avO + m*68 + dq*4) = ((const float4*)(ws + WS_AVO + b*4096))[f];
  }
  __syncthreads();

  // ---- ph7: S = w @ avA (threads 0..127); wavo = wo @ avO (128..255) -----
  if (t < 128) {
    const int i = t >> 4, dq = (t & 15) << 2;
    float4 acc = {0,0,0,0};
    #pragma unroll 4
    for (int k = 0; k < 32; ++k) {
      float4 a4 = *(const float4*)(s_avA + k*68 + dq);
      float wv = s_w[i*36 + k];
      acc.x += wv*a4.x; acc.y += wv*a4.y; acc.z += wv*a4.z; acc.w += wv*a4.w;
    }
    *(float4*)(s_S + i*68 + dq) = acc;
  } else {
    const int tt2 = t - 128;
    const int i = tt2 >> 4, dq = (tt2 & 15) << 2;
    float4 acc = {0,0,0,0};
    #pragma unroll 4
    for (int m = 0; m < 64; ++m) {
      float4 a4 = *(const float4*)(s_avO + m*68 + dq);
      float wv = s_wo[i*68 + m];
      acc.x += wv*a4.x; acc.y += wv*a4.y; acc.z += wv*a4.z; acc.w += wv*a4.w;
    }
    *(float4*)(s_wavo + i*68 + dq) = acc;
  }
  __syncthreads();

  // ---- ph8: base = S@Wf1a + wavo@Wf1b ------------------------------------
  {
    const int h = t & 63, g = (t >> 6) << 1;
    float a0 = 0.f, a1 = 0.f;
    #pragma unroll 4
    for (int d = 0; d < 64; ++d) {
      float w1v = W_f1[d*64 + h];
      float w2v = W_f1[(64 + d)*64 + h];
      a0 += s_S[g*68 + d]*w1v + s_wavo[g*68 + d]*w2v;
      a1 += s_S[(g+1)*68 + d]*w1v + s_wavo[(g+1)*68 + d]*w2v;
    }
    s_base[g*68 + h] = a0;
    s_base[(g+1)*68 + h] = a1;
  }
  __syncthreads();

  // ---- ph9: value[i][j] = sum_h lrelu(base[i,h]+w[i,j]*dproj[j,h])*Wf2[h] -
  {
    const int i = t >> 5, j = t & 31;
    const float wij = s_w[i*36 + j];
    float acc = 0.f;
    #pragma unroll 4
    for (int hq = 0; hq < 16; ++hq) {
      float4 b4 = *(const float4*)(s_base + i*68 + hq*4);
      float4 d4 = *(const float4*)(s_dp + j*68 + hq*4);
      float4 f4 = *(const float4*)(s_wf2 + hq*4);
      float p0 = b4.x + wij*d4.x; p0 = p0 > 0.f ? p0 : 0.01f*p0;
      float p1 = b4.y + wij*d4.y; p1 = p1 > 0.f ? p1 : 0.01f*p1;
      float p2 = b4.z + wij*d4.z; p2 = p2 > 0.f ? p2 : 0.01f*p2;
      float p3 = b4.w + wij*d4.w; p3 = p3 > 0.f ? p3 : 0.01f*p3;
      acc += p0*f4.x + p1*f4.y + p2*f4.z + p3*f4.w;
    }
    out[b*1024 + (i0 + i)*32 + j] = acc;
  }
}

extern "C" void kernel_launch(void* const* d_in, const int* in_sizes, int n_in,
                              void* d_out, int out_size, void* d_ws, size_t ws_size,
                              hipStream_t stream) {
  const float* states        = (const float*)d_in[0];
  const float* policies      = (const float*)d_in[1];
  const float* actions       = (const float*)d_in[2];
  const float* states_other  = (const float*)d_in[3];
  const float* actions_other = (const float*)d_in[4];
  const float* W_key         = (const float*)d_in[5];
  const float* W_query       = (const float*)d_in[6];
  const float* W_av          = (const float*)d_in[7];
  const float* W_key_other   = (const float*)d_in[8];
  const float* W_query_other = (const float*)d_in[9];
  const float* W_av_other    = (const float*)d_in[10];
  const float* W_f1          = (const float*)d_in[11];
  const float* W_f2          = (const float*)d_in[12];
  float* out = (float*)d_out;
  float* ws  = (float*)d_ws;   // 4.125 MB used

  k1_pre<<<416, 256, 0, stream>>>(states, policies, actions, states_other,
                                  actions_other, W_query, W_key,
                                  W_query_other, W_key_other, W_av, W_av_other,
                                  W_f1, ws);
  k2_main<<<512, 256, 0, stream>>>(states, states_other, W_f1, W_f2, ws, out);
}

// Round 4
// 127.481 us; speedup vs baseline: 1.3399x; 1.0372x over previous
//
#include <hip/hip_runtime.h>
#include <math.h>

// Problem constants (fixed by reference)
//  B=128, N=32, M=64, OBS=128, ACT=16, D_QK=128, D_AV=64, F_IN=144, H=64
// Outputs concatenated: value [B,32,32] @0, ret_weight [B,32,32] @131072,
// weight_other [B,32,64] @262144.
//
// Workspace (floats), 1,081,344 floats = 4.125 MB:
#define WS_WQK   0         // [128][128]
#define WS_WQKO  16384     // [128][128]
#define WS_AVA   32768     // [B][32][64]
#define WS_AVO   294912    // [B][64][64]
#define WS_DPROJ 819200    // [B][32][64]

#define INV_SQRT_DK 0.08838834764831845f  // 1/sqrt(128)

__device__ __forceinline__ float dot4(float4 a, float4 b) {
  return a.x*b.x + a.y*b.y + a.z*b.z + a.w*b.w;
}
__device__ __forceinline__ void fma4(float4& a, const float4 w, const float s) {
  a.x += w.x*s; a.y += w.y*s; a.z += w.z*s; a.w += w.w*s;
}

// ---------------------------------------------------------------------------
// K1: independent pre-work. grid 416:
//   [0,32)    Wqk / Wqko fusion tiles (32x32 out each)
//   [32,160)  avA + delta + dproj per b   (scalar-uniform input reads)
//   [160,416) avO per (b, m-half)         (no LDS at all)
// ---------------------------------------------------------------------------
__global__ __launch_bounds__(256) void k1_pre(
    const float* __restrict__ g_states, const float* __restrict__ g_pol,
    const float* __restrict__ g_act, const float* __restrict__ g_so,
    const float* __restrict__ g_ao,
    const float* __restrict__ Wq, const float* __restrict__ Wk,
    const float* __restrict__ Wqo, const float* __restrict__ Wko,
    const float* __restrict__ W_av, const float* __restrict__ W_avo,
    const float* __restrict__ W_f1, float* __restrict__ ws)
{
  __shared__ __align__(16) float pool[8448];   // 33 KB
  const int t = threadIdx.x;
  int blk = blockIdx.x;

  if (blk < 32) {
    // ---- weight fusion: Wqk[c][e] = sum_d Wq[c,d]*Wk[e,d] ----------------
    const float* A; const float* Bm; float* O;
    if (blk < 16) { A = Wq;  Bm = Wk;  O = ws + WS_WQK; }
    else          { A = Wqo; Bm = Wko; O = ws + WS_WQKO; blk -= 16; }
    const int tr = (blk >> 2) << 5;   // output row tile (c)
    const int tc = (blk & 3) << 5;    // output col tile (e)
    float* sA = pool;                 // [32][132]
    float* sB = pool + 4224;          // [32][132]
    const float4* a4 = (const float4*)(A + tr * 128);
    const float4* b4 = (const float4*)(Bm + tc * 128);
    #pragma unroll
    for (int u = 0; u < 4; ++u) {
      int f = t + u * 256;
      int r = f >> 5, c4 = f & 31;
      *(float4*)(sA + r*132 + c4*4) = a4[f];
      *(float4*)(sB + r*132 + c4*4) = b4[f];
    }
    __syncthreads();
    const int e = t & 31, cl0 = t >> 5;
    float acc[4] = {0,0,0,0};
    #pragma unroll 4
    for (int d4 = 0; d4 < 32; ++d4) {
      float4 bv = *(const float4*)(sB + e*132 + d4*4);
      #pragma unroll
      for (int rr = 0; rr < 4; ++rr) {
        float4 av = *(const float4*)(sA + (cl0 + rr*8)*132 + d4*4);
        acc[rr] += dot4(av, bv);
      }
    }
    #pragma unroll
    for (int rr = 0; rr < 4; ++rr)
      O[(tr + cl0 + rr*8)*128 + tc + e] = acc[rr];
    return;
  }
  blk -= 32;

  if (blk < 128) {
    // ---- avA + delta + dproj per b ---------------------------------------
    // wave = (ap, row-half); lane = d-column. Input rows read as scalar
    // (wave-uniform) loads; W_av streamed coalesced, 4x redundancy only.
    const int b = blk;
    float* s_pre = pool;          // [32][132]: pre-act A at +0, P at +64
    float* s_dl  = pool + 4224;   // delta [32][68]
    {
      const int wv_  = t >> 6;          // wave 0..3
      const int ap   = wv_ & 1;         // 0 = actions, 1 = policies
      const int rh   = wv_ >> 1;        // row half (16 rows)
      const int lane = t & 63;          // d column
      const float* gs = g_states + b*4096 + rh*16*128;
      const float* gt = (ap ? g_pol : g_act) + b*512 + rh*16*16;
      float acc[16];
      #pragma unroll
      for (int r = 0; r < 16; ++r) acc[r] = 0.f;
      #pragma unroll 4
      for (int c4 = 0; c4 < 32; ++c4) {          // shared c < 128
        const float w0 = W_av[(c4*4+0)*64 + lane];
        const float w1 = W_av[(c4*4+1)*64 + lane];
        const float w2 = W_av[(c4*4+2)*64 + lane];
        const float w3 = W_av[(c4*4+3)*64 + lane];
        #pragma unroll
        for (int r = 0; r < 16; ++r) {
          float4 sv = *(const float4*)(gs + r*128 + c4*4);  // scalar (uniform)
          acc[r] += sv.x*w0 + sv.y*w1 + sv.z*w2 + sv.w*w3;
        }
      }
      #pragma unroll
      for (int c4 = 0; c4 < 4; ++c4) {           // tail c in [128,144)
        const float w0 = W_av[(128 + c4*4+0)*64 + lane];
        const float w1 = W_av[(128 + c4*4+1)*64 + lane];
        const float w2 = W_av[(128 + c4*4+2)*64 + lane];
        const float w3 = W_av[(128 + c4*4+3)*64 + lane];
        #pragma unroll
        for (int r = 0; r < 16; ++r) {
          float4 sv = *(const float4*)(gt + r*16 + c4*4);
          acc[r] += sv.x*w0 + sv.y*w1 + sv.z*w2 + sv.w*w3;
        }
      }
      #pragma unroll
      for (int r = 0; r < 16; ++r)
        s_pre[(rh*16 + r)*132 + ap*64 + lane] = acc[r];
    }
    __syncthreads();
    {
      // combine: avA = tanh(preA); delta = tanh(preP) - avA
      const int r = t >> 3, d0 = (t & 7) << 3;
      float4 a0 = *(const float4*)(s_pre + r*132 + d0);
      float4 a1 = *(const float4*)(s_pre + r*132 + d0 + 4);
      float4 p0 = *(const float4*)(s_pre + r*132 + 64 + d0);
      float4 p1 = *(const float4*)(s_pre + r*132 + 64 + d0 + 4);
      float4 va0, va1, dl0, dl1;
      va0.x = tanhf(a0.x); va0.y = tanhf(a0.y); va0.z = tanhf(a0.z); va0.w = tanhf(a0.w);
      va1.x = tanhf(a1.x); va1.y = tanhf(a1.y); va1.z = tanhf(a1.z); va1.w = tanhf(a1.w);
      dl0.x = tanhf(p0.x) - va0.x; dl0.y = tanhf(p0.y) - va0.y;
      dl0.z = tanhf(p0.z) - va0.z; dl0.w = tanhf(p0.w) - va0.w;
      dl1.x = tanhf(p1.x) - va1.x; dl1.y = tanhf(p1.y) - va1.y;
      dl1.z = tanhf(p1.z) - va1.z; dl1.w = tanhf(p1.w) - va1.w;
      *(float4*)(ws + WS_AVA + b*2048 + r*64 + d0)     = va0;
      *(float4*)(ws + WS_AVA + b*2048 + r*64 + d0 + 4) = va1;
      *(float4*)(s_dl + r*68 + d0)     = dl0;
      *(float4*)(s_dl + r*68 + d0 + 4) = dl1;
    }
    __syncthreads();
    {
      // dproj[j][h] = sum_d delta[j][d] * W_f1[d][h]
      const int h = t & 63;
      const int j0 = (t >> 6) << 3;     // 8 rows per thread
      float acc[8] = {0,0,0,0,0,0,0,0};
      #pragma unroll 4
      for (int d4 = 0; d4 < 16; ++d4) {
        float w0 = W_f1[(d4*4+0)*64 + h];
        float w1 = W_f1[(d4*4+1)*64 + h];
        float w2 = W_f1[(d4*4+2)*64 + h];
        float w3 = W_f1[(d4*4+3)*64 + h];
        #pragma unroll
        for (int q = 0; q < 8; ++q) {
          float4 dv = *(const float4*)(s_dl + (j0+q)*68 + d4*4);
          acc[q] += dv.x*w0 + dv.y*w1 + dv.z*w2 + dv.w*w3;
        }
      }
      #pragma unroll
      for (int q = 0; q < 8; ++q)
        ws[WS_DPROJ + b*2048 + (j0+q)*64 + h] = acc[q];
    }
    return;
  }
  blk -= 128;

  // ---- avO per (b, 32-row half): wave = 8-row group, lane = d ------------
  {
    const int b = blk >> 1, m0 = (blk & 1) << 5;
    const int wv_  = t >> 6;            // 0..3: 8-row group
    const int lane = t & 63;
    const float* gso = g_so + (b*64 + m0 + wv_*8) * 128;
    const float* gao = g_ao + (b*64 + m0 + wv_*8) * 16;
    float acc[8];
    #pragma unroll
    for (int r = 0; r < 8; ++r) acc[r] = 0.f;
    #pragma unroll 4
    for (int c4 = 0; c4 < 32; ++c4) {
      const float w0 = W_avo[(c4*4+0)*64 + lane];
      const float w1 = W_avo[(c4*4+1)*64 + lane];
      const float w2 = W_avo[(c4*4+2)*64 + lane];
      const float w3 = W_avo[(c4*4+3)*64 + lane];
      #pragma unroll
      for (int r = 0; r < 8; ++r) {
        float4 sv = *(const float4*)(gso + r*128 + c4*4);  // scalar (uniform)
        acc[r] += sv.x*w0 + sv.y*w1 + sv.z*w2 + sv.w*w3;
      }
    }
    #pragma unroll
    for (int c4 = 0; c4 < 4; ++c4) {
      const float w0 = W_avo[(128 + c4*4+0)*64 + lane];
      const float w1 = W_avo[(128 + c4*4+1)*64 + lane];
      const float w2 = W_avo[(128 + c4*4+2)*64 + lane];
      const float w3 = W_avo[(128 + c4*4+3)*64 + lane];
      #pragma unroll
      for (int r = 0; r < 8; ++r) {
        float4 sv = *(const float4*)(gao + r*16 + c4*4);
        acc[r] += sv.x*w0 + sv.y*w1 + sv.z*w2 + sv.w*w3;
      }
    }
    #pragma unroll
    for (int r = 0; r < 8; ++r)
      ws[WS_AVO + b*4096 + (m0 + wv_*8 + r)*64 + lane] = tanhf(acc[r]);
  }
}

// ---------------------------------------------------------------------------
// K2: everything after pre-work, per (b, i-octile). grid 512.
// LDS pool (floats), 17472 = 68.25 KB (2 blocks/CU):
//   A    @0     [4352]: states [32][132] / so tiles [32][132] / avO [64][68]
//   RED  @4352  [8448]: ph2 partials [4][8][66]xf4; later avA[32][68]@4352,
//                        dproj [32][68] @6528
//   P    @12800 [2144]: [8][268]  (P1 cols 0..127, P2 cols 128..255)
//   w    @14944 [288] : [8][36]
//   wo   @15232 [544] : [8][68]
//   S    @15776 [544] : [8][68]
//   wavo @16320 [544]
//   base @16864 [544]
//   wf2  @17408 [64]
// ---------------------------------------------------------------------------
__global__ __launch_bounds__(256) void k2_main(
    const float* __restrict__ g_states, const float* __restrict__ g_so,
    const float* __restrict__ W_f1, const float* __restrict__ W_f2,
    const float* __restrict__ ws, float* __restrict__ out)
{
  __shared__ __align__(16) float pool[17472];
  float* s_st   = pool;
  float* s_red  = pool + 4352;
  float* s_avA  = pool + 4352;     // alias RED (dead after ph2)
  float* s_dp   = pool + 6528;     // alias RED
  float* s_avO  = pool;            // alias A (dead after ph5)
  float* s_P    = pool + 12800;
  float* s_w    = pool + 14944;
  float* s_wo   = pool + 15232;
  float* s_S    = pool + 15776;
  float* s_wavo = pool + 16320;
  float* s_base = pool + 16864;
  float* s_wf2  = pool + 17408;

  const int t = threadIdx.x;
  const int b = blockIdx.x >> 2;
  const int i0 = (blockIdx.x & 3) << 3;

  // ---- ph1: stage states (for ph3 j-side), wf2 ---------------------------
  {
    const float4* gs4 = (const float4*)(g_states + b * 4096);
    #pragma unroll
    for (int u = 0; u < 4; ++u) {
      int f = t + u * 256;
      int r = f >> 5, c4 = f & 31;
      *(float4*)(s_st + r*132 + c4*4) = gs4[f];
    }
    if (t < 16) *(float4*)(s_wf2 + t*4) = ((const float4*)W_f2)[t];
  }

  // ---- ph2: P = states[i0..+8] @ [Wqk|Wqko], no-redundancy scheme --------
  // wave = K-chunk (32 c), lane = f4-column of [P1|P2]; states via scalar
  // (uniform) loads, W read exactly once per (chunk, column).
  {
    const int wave = t >> 6;
    const int col  = t & 63;             // <32: Wqk/P1, >=32: Wqko/P2
    const float* Wp = (col < 32) ? (ws + WS_WQK + col*4)
                                 : (ws + WS_WQKO + (col-32)*4);
    const float* srow = g_states + b*4096 + i0*128 + wave*32;
    float4 acc[8];
    #pragma unroll
    for (int r = 0; r < 8; ++r) acc[r] = make_float4(0.f,0.f,0.f,0.f);
    #pragma unroll 2
    for (int c4 = 0; c4 < 8; ++c4) {
      float4 sv[8];
      #pragma unroll
      for (int r = 0; r < 8; ++r)
        sv[r] = *(const float4*)(srow + r*128 + c4*4);   // scalar (uniform)
      #pragma unroll
      for (int k = 0; k < 4; ++k) {
        float4 wv = *(const float4*)(Wp + (wave*32 + c4*4 + k)*128);
        #pragma unroll
        for (int r = 0; r < 8; ++r)
          fma4(acc[r], wv, ((const float*)&sv[r])[k]);
      }
    }
    #pragma unroll
    for (int r = 0; r < 8; ++r)
      *(float4*)(s_red + ((wave*8 + r)*66 + col)*4) = acc[r];
  }
  __syncthreads();
  {
    // reduce 4 K-chunk partials -> P [8][268]
    const int r = t >> 5, cp = t & 31;
    #pragma unroll
    for (int s2 = 0; s2 < 2; ++s2) {
      const int col = cp*2 + s2;
      float4 a0 = *(const float4*)(s_red + ((0*8 + r)*66 + col)*4);
      float4 a1 = *(const float4*)(s_red + ((1*8 + r)*66 + col)*4);
      float4 a2 = *(const float4*)(s_red + ((2*8 + r)*66 + col)*4);
      float4 a3 = *(const float4*)(s_red + ((3*8 + r)*66 + col)*4);
      float4 s4;
      s4.x = (a0.x + a1.x) + (a2.x + a3.x);
      s4.y = (a0.y + a1.y) + (a2.y + a3.y);
      s4.z = (a0.z + a1.z) + (a2.z + a3.z);
      s4.w = (a0.w + a1.w) + (a2.w + a3.w);
      *(float4*)(s_P + r*268 + col*4) = s4;
    }
  }
  __syncthreads();

  // ---- ph3: self scores + register softmax + write ret_weight ------------
  {
    const int r = t >> 5, j = t & 31;
    float acc = 0.f;
    #pragma unroll 8
    for (int e4 = 0; e4 < 32; ++e4) {
      float4 p4  = *(const float4*)(s_P + r*268 + e4*4);
      float4 st4 = *(const float4*)(s_st + j*132 + e4*4);
      acc += dot4(p4, st4);
    }
    acc *= INV_SQRT_DK;
    float mx = acc;
    for (int off = 16; off; off >>= 1) mx = fmaxf(mx, __shfl_xor(mx, off, 32));
    float ev = __expf(acc - mx);
    float sum = ev;
    for (int off = 16; off; off >>= 1) sum += __shfl_xor(sum, off, 32);
    float wn = ev / sum;
    out[131072 + b*1024 + (i0 + r)*32 + j] = wn;
    s_w[r*36 + j] = wn;
  }
  __syncthreads();

  // ---- ph4/5: other scores over two states_other tiles -------------------
  for (int tt = 0; tt < 2; ++tt) {
    const float4* gt4 = (const float4*)(g_so + (b*64 + tt*32) * 128);
    #pragma unroll
    for (int u = 0; u < 4; ++u) {
      int f = t + u * 256;
      int r = f >> 5, c4 = f & 31;
      *(float4*)(s_st + r*132 + c4*4) = gt4[f];
    }
    __syncthreads();
    const int r = t >> 5, m = t & 31;
    float acc = 0.f;
    #pragma unroll 8
    for (int c4 = 0; c4 < 32; ++c4) {
      float4 p4  = *(const float4*)(s_P + r*268 + 128 + c4*4);
      float4 st4 = *(const float4*)(s_st + m*132 + c4*4);
      acc += dot4(p4, st4);
    }
    s_wo[r*68 + tt*32 + m] = acc * INV_SQRT_DK;
    __syncthreads();
  }

  // ---- ph6: softmax wo + write weight_other; stage avA/avO/dproj ---------
  #pragma unroll
  for (int p = 0; p < 2; ++p) {
    const int r = (t >> 6) + (p << 2), l = t & 63;
    float v = s_wo[r*68 + l];
    float mx = v;
    for (int off = 32; off; off >>= 1) mx = fmaxf(mx, __shfl_xor(mx, off, 64));
    float ev = __expf(v - mx);
    float sum = ev;
    for (int off = 32; off; off >>= 1) sum += __shfl_xor(sum, off, 64);
    float wn = ev / sum;
    out[262144 + b*2048 + (i0 + r)*64 + l] = wn;
    s_wo[r*68 + l] = wn;
  }
  #pragma unroll
  for (int u = 0; u < 2; ++u) {
    int f = t + u * 256;
    int k = f >> 4, dq = f & 15;
    *(float4*)(s_avA + k*68 + dq*4) = ((const float4*)(ws + WS_AVA + b*2048))[f];
    *(float4*)(s_dp  + k*68 + dq*4) = ((const float4*)(ws + WS_DPROJ + b*2048))[f];
  }
  #pragma unroll
  for (int u = 0; u < 4; ++u) {
    int f = t + u * 256;
    int m = f >> 4, dq = f & 15;
    *(float4*)(s_avO + m*68 + dq*4) = ((const float4*)(ws + WS_AVO + b*4096))[f];
  }
  __syncthreads();

  // ---- ph7: S = w @ avA (threads 0..127); wavo = wo @ avO (128..255) -----
  if (t < 128) {
    const int i = t >> 4, dq = (t & 15) << 2;
    float4 acc = {0,0,0,0};
    #pragma unroll 4
    for (int k = 0; k < 32; ++k) {
      float4 a4 = *(const float4*)(s_avA + k*68 + dq);
      float wv = s_w[i*36 + k];
      acc.x += wv*a4.x; acc.y += wv*a4.y; acc.z += wv*a4.z; acc.w += wv*a4.w;
    }
    *(float4*)(s_S + i*68 + dq) = acc;
  } else {
    const int tt2 = t - 128;
    const int i = tt2 >> 4, dq = (tt2 & 15) << 2;
    float4 acc = {0,0,0,0};
    #pragma unroll 4
    for (int m = 0; m < 64; ++m) {
      float4 a4 = *(const float4*)(s_avO + m*68 + dq);
      float wv = s_wo[i*68 + m];
      acc.x += wv*a4.x; acc.y += wv*a4.y; acc.z += wv*a4.z; acc.w += wv*a4.w;
    }
    *(float4*)(s_wavo + i*68 + dq) = acc;
  }
  __syncthreads();

  // ---- ph8: base = S@Wf1a + wavo@Wf1b ------------------------------------
  {
    const int h = t & 63, g = (t >> 6) << 1;
    float a0 = 0.f, a1 = 0.f;
    #pragma unroll 4
    for (int d = 0; d < 64; ++d) {
      float w1v = W_f1[d*64 + h];
      float w2v = W_f1[(64 + d)*64 + h];
      a0 += s_S[g*68 + d]*w1v + s_wavo[g*68 + d]*w2v;
      a1 += s_S[(g+1)*68 + d]*w1v + s_wavo[(g+1)*68 + d]*w2v;
    }
    s_base[g*68 + h] = a0;
    s_base[(g+1)*68 + h] = a1;
  }
  __syncthreads();

  // ---- ph9: value[i][j] = sum_h lrelu(base[i,h]+w[i,j]*dproj[j,h])*Wf2[h] -
  {
    const int i = t >> 5, j = t & 31;
    const float wij = s_w[i*36 + j];
    float acc = 0.f;
    #pragma unroll 4
    for (int hq = 0; hq < 16; ++hq) {
      float4 b4 = *(const float4*)(s_base + i*68 + hq*4);
      float4 d4 = *(const float4*)(s_dp + j*68 + hq*4);
      float4 f4 = *(const float4*)(s_wf2 + hq*4);
      float p0 = b4.x + wij*d4.x; p0 = p0 > 0.f ? p0 : 0.01f*p0;
      float p1 = b4.y + wij*d4.y; p1 = p1 > 0.f ? p1 : 0.01f*p1;
      float p2 = b4.z + wij*d4.z; p2 = p2 > 0.f ? p2 : 0.01f*p2;
      float p3 = b4.w + wij*d4.w; p3 = p3 > 0.f ? p3 : 0.01f*p3;
      acc += p0*f4.x + p1*f4.y + p2*f4.z + p3*f4.w;
    }
    out[b*1024 + (i0 + i)*32 + j] = acc;
  }
}

extern "C" void kernel_launch(void* const* d_in, const int* in_sizes, int n_in,
                              void* d_out, int out_size, void* d_ws, size_t ws_size,
                              hipStream_t stream) {
  const float* states        = (const float*)d_in[0];
  const float* policies      = (const float*)d_in[1];
  const float* actions       = (const float*)d_in[2];
  const float* states_other  = (const float*)d_in[3];
  const float* actions_other = (const float*)d_in[4];
  const float* W_key         = (const float*)d_in[5];
  const float* W_query       = (const float*)d_in[6];
  const float* W_av          = (const float*)d_in[7];
  const float* W_key_other   = (const float*)d_in[8];
  const float* W_query_other = (const float*)d_in[9];
  const float* W_av_other    = (const float*)d_in[10];
  const float* W_f1          = (const float*)d_in[11];
  const float* W_f2          = (const float*)d_in[12];
  float* out = (float*)d_out;
  float* ws  = (float*)d_ws;   // 4.125 MB used

  k1_pre<<<416, 256, 0, stream>>>(states, policies, actions, states_other,
                                  actions_other, W_query, W_key,
                                  W_query_other, W_key_other, W_av, W_av_other,
                                  W_f1, ws);
  k2_main<<<512, 256, 0, stream>>>(states, states_other, W_f1, W_f2, ws, out);
}